// Round 3
// baseline (863.827 us; speedup 1.0000x reference)
//
#include <hip/hip_runtime.h>
#include <cstdint>
#include <cstddef>

// Problem constants
#define BB 4
#define SS 4096
#define DD 1024
#define HH 16
#define MM (BB*SS)          // 16384 rows

typedef __bf16 bf16x8 __attribute__((ext_vector_type(8)));
typedef float  f32x4  __attribute__((ext_vector_type(4)));

__device__ __forceinline__ float b2f(unsigned short h){
    union { unsigned int u; float f; } c; c.u = ((unsigned int)h) << 16; return c.f;
}
__device__ __forceinline__ unsigned short f2b(float f){
    union { float f; unsigned int u; } c; c.f = f;
    unsigned int u = c.u + 0x7FFFu + ((c.u >> 16) & 1u);   // RNE
    return (unsigned short)(u >> 16);
}

// ---------------------------------------------------------------- zero scratch
__global__ void zero_f32(float* __restrict__ p, int n){
    int i = blockIdx.x*256 + threadIdx.x;
    if(i < n) p[i] = 0.0f;
}

// ---------------------------------------------------------------- transpose+cvt
// dst[n*K+k] = bf16(src[k*N+n])   (weights -> [N,K] bf16 so GEMM B-frags read contiguous k)
__global__ void transpose_cvt(const float* __restrict__ src, unsigned short* __restrict__ dst,
                              int K, int N){
    __shared__ float tile[32][33];
    int kb = blockIdx.y*32, nb = blockIdx.x*32;
    int tx = threadIdx.x, ty = threadIdx.y;
    for(int i=0;i<32;i+=8) tile[ty+i][tx] = src[(size_t)(kb+ty+i)*N + nb+tx];
    __syncthreads();
    for(int i=0;i<32;i+=8) dst[(size_t)(nb+ty+i)*K + kb+tx] = f2b(tile[tx][ty+i]);
}

// ---------------------------------------------------------------- layernorm (+ optional sinusoidal PE)
__global__ __launch_bounds__(256) void ln_kernel(const float* __restrict__ x,
                                                 const float* __restrict__ g,
                                                 const float* __restrict__ bta,
                                                 unsigned short* __restrict__ out,
                                                 int add_pe){
    int row = blockIdx.x;
    int t = threadIdx.x;
    float4 v = ((const float4*)(x + (size_t)row*DD))[t];
    float s = v.x+v.y+v.z+v.w;
    float q = v.x*v.x+v.y*v.y+v.z*v.z+v.w*v.w;
    for(int off=32; off>0; off>>=1){ s += __shfl_xor(s, off); q += __shfl_xor(q, off); }
    __shared__ float red[8];
    int wv = t>>6, ln = t&63;
    if(ln==0){ red[wv] = s; red[4+wv] = q; }
    __syncthreads();
    s = red[0]+red[1]+red[2]+red[3];
    q = red[4]+red[5]+red[6]+red[7];
    float mu = s * (1.0f/1024.0f);
    float var = q * (1.0f/1024.0f) - mu*mu;
    float rs = rsqrtf(var + 1e-6f);
    int d0 = t*4;
    float4 gg = ((const float4*)g)[t];
    float4 bb = ((const float4*)bta)[t];
    float o0 = (v.x-mu)*rs*gg.x + bb.x;
    float o1 = (v.y-mu)*rs*gg.y + bb.y;
    float o2 = (v.z-mu)*rs*gg.z + bb.z;
    float o3 = (v.w-mu)*rs*gg.w + bb.w;
    if(add_pe){
        // PE[s, e]   (e even) = sin(s * exp(cfac*e)),  PE[s, e+1] = cos(same)
        // cfac = -ln(10000)/1024 ; element pair (d0,d0+1) uses exp(cfac*d0),
        // pair (d0+2,d0+3) uses exp(cfac*(d0+2)).  [R2 bug: had 2*d0]
        int sidx = row & (SS-1);
        const float cfac = -0.008994473019508968f;   // -ln(10000)/1024
        float a0 = (float)sidx * expf(cfac * (float)(d0));
        float a1 = (float)sidx * expf(cfac * (float)(d0 + 2));
        o0 += sinf(a0); o1 += cosf(a0);
        o2 += sinf(a1); o3 += cosf(a1);
    }
    ushort4 o;
    o.x = f2b(o0); o.y = f2b(o1); o.z = f2b(o2); o.w = f2b(o3);
    *(ushort4*)(out + (size_t)row*DD + d0) = o;
}

// ---------------------------------------------------------------- bf16 MFMA GEMM  C = A[M,K] * Bt[N,K]^T
// EPI 0: store bf16(acc)
// EPI 1: store bf16(gelu(acc+bias[col]))            (exact erf gelu)
// EPI 2: store fp32(acc + bias[col] + resid[row,col])
template<int EPI>
__global__ __launch_bounds__(256, 2) void gemm_bt(
        const unsigned short* __restrict__ A,
        const unsigned short* __restrict__ Bt,
        void* __restrict__ Cout,
        const float* __restrict__ bias,
        const float* __restrict__ resid,
        int M, int N, int K)
{
    __shared__ __align__(16) unsigned short lA[128*64];
    __shared__ __align__(16) unsigned short lB[128*64];
    const int tid  = threadIdx.x;
    const int lane = tid & 63;
    const int wave = tid >> 6;
    const int quad = lane >> 4;
    const int l16  = lane & 15;
    const int wr = wave >> 1, wc = wave & 1;
    const int m0 = blockIdx.y * 128;
    const int n0 = blockIdx.x * 128;

    f32x4 acc[4][4] = {};

    for (int k0 = 0; k0 < K; k0 += 64) {
        __syncthreads();
        #pragma unroll
        for (int i = 0; i < 4; i++) {
            int c   = tid + 256*i;
            int row = c >> 3;
            int kc  = ((c & 7) ^ (row & 7)) << 3;          // XOR swizzle (elements)
            const unsigned short* gA = A  + (size_t)(m0 + row) * K + k0 + kc;
            const unsigned short* gB = Bt + (size_t)(n0 + row) * K + k0 + kc;
            char* lpA = ((char*)lA) + (wave<<10) + (i<<12); // wave-uniform base; HW adds lane*16
            char* lpB = ((char*)lB) + (wave<<10) + (i<<12);
            __builtin_amdgcn_global_load_lds((const __attribute__((address_space(1))) void*)gA,
                                             (__attribute__((address_space(3))) void*)lpA, 16, 0, 0);
            __builtin_amdgcn_global_load_lds((const __attribute__((address_space(1))) void*)gB,
                                             (__attribute__((address_space(3))) void*)lpB, 16, 0, 0);
        }
        __syncthreads();
        #pragma unroll
        for (int kk = 0; kk < 2; kk++) {
            bf16x8 af[4], bfr[4];
            #pragma unroll
            for (int mi = 0; mi < 4; mi++) {
                int row = wr*64 + mi*16 + l16;
                int kb  = (kk*64 + quad*16) ^ ((row & 7) << 4);
                af[mi] = *(const bf16x8*)((const char*)lA + row*128 + kb);
            }
            #pragma unroll
            for (int ni = 0; ni < 4; ni++) {
                int row = wc*64 + ni*16 + l16;
                int kb  = (kk*64 + quad*16) ^ ((row & 7) << 4);
                bfr[ni] = *(const bf16x8*)((const char*)lB + row*128 + kb);
            }
            #pragma unroll
            for (int mi = 0; mi < 4; mi++)
                #pragma unroll
                for (int ni = 0; ni < 4; ni++)
                    acc[mi][ni] = __builtin_amdgcn_mfma_f32_16x16x32_bf16(af[mi], bfr[ni], acc[mi][ni], 0, 0, 0);
        }
    }

    #pragma unroll
    for (int mi = 0; mi < 4; mi++) {
        #pragma unroll
        for (int r = 0; r < 4; r++) {
            int grow = m0 + wr*64 + mi*16 + quad*4 + r;
            #pragma unroll
            for (int ni = 0; ni < 4; ni++) {
                int gcol = n0 + wc*64 + ni*16 + l16;
                float v = acc[mi][ni][r];
                size_t idx = (size_t)grow * N + gcol;
                if (EPI == 0) {
                    ((unsigned short*)Cout)[idx] = f2b(v);
                } else if (EPI == 1) {
                    v += bias[gcol];
                    v = 0.5f * v * (1.0f + erff(v * 0.70710678118654752f));
                    ((unsigned short*)Cout)[idx] = f2b(v);
                } else {
                    v += bias[gcol] + resid[idx];
                    ((float*)Cout)[idx] = v;
                }
            }
        }
    }
}

// ---------------------------------------------------------------- q softmax (over dh=64, per head) * dh^-0.5
// in-place on the Q section of QKV [M,3072]
__global__ __launch_bounds__(256) void q_softmax(unsigned short* __restrict__ qkv){
    int r = blockIdx.x;
    int lane = threadIdx.x & 63, wv = threadIdx.x >> 6;
    unsigned short* qr = qkv + (size_t)r*3072;
    for(int h = wv; h < HH; h += 4){
        float v = b2f(qr[h*64 + lane]);
        float m = v;
        for(int off=32; off>0; off>>=1) m = fmaxf(m, __shfl_xor(m, off));
        float e = expf(v - m);
        float ssum = e;
        for(int off=32; off>0; off>>=1) ssum += __shfl_xor(ssum, off);
        qr[h*64 + lane] = f2b(e/ssum * 0.125f);
    }
}

// ---------------------------------------------------------------- k softmax over S: pass 1 (column sums of exp)
__global__ __launch_bounds__(256) void k_colsum(const unsigned short* __restrict__ qkv,
                                                float* __restrict__ colsum){
    int cg = blockIdx.x, rc = blockIdx.y, b = blockIdx.z;
    int t = threadIdx.x;
    int col = cg*64 + (t & 63);               // col within k-section [0,1024)
    int r0 = b*SS + rc*256 + (t >> 6);
    float s = 0.0f;
    for(int j=0;j<64;j++){
        int r = r0 + j*4;
        s += expf(b2f(qkv[(size_t)r*3072 + DD + col]));
    }
    __shared__ float red[256];
    red[t] = s; __syncthreads();
    if(t < 64){
        float tot = red[t] + red[t+64] + red[t+128] + red[t+192];
        atomicAdd(&colsum[b*DD + cg*64 + t], tot);
    }
}

// pass 2: normalize -> bf16, in-place on K section of QKV
__global__ __launch_bounds__(256) void k_norm(unsigned short* __restrict__ qkv,
                                              const float* __restrict__ colsum){
    int r = blockIdx.x, t = threadIdx.x;
    int b = r >> 12;
    unsigned short* kr = qkv + (size_t)r*3072 + DD;
    ushort4 in = *(const ushort4*)(kr + t*4);
    const float* cs = colsum + b*DD + t*4;
    ushort4 o;
    o.x = f2b(expf(b2f(in.x)) / cs[0]);
    o.y = f2b(expf(b2f(in.y)) / cs[1]);
    o.z = f2b(expf(b2f(in.z)) / cs[2]);
    o.w = f2b(expf(b2f(in.w)) / cs[3]);
    *(ushort4*)(kr + t*4) = o;
}

// ---------------------------------------------------------------- context[b,h,d,e] += sum_s k[s,d]*v[s,e]
// k and v both read from QKV (k already normalized in-place)
__global__ __launch_bounds__(256) void ctx_partial(const unsigned short* __restrict__ qkv,
                                                   float* __restrict__ ctx){
    int sc = blockIdx.x, h = blockIdx.y, b = blockIdx.z;
    int t = threadIdx.x;
    __shared__ __align__(16) float kl[64][64];
    __shared__ __align__(16) float vl[64][64];
    float acc[16] = {};
    int e = t & 63, dg = (t >> 6) * 16;
    for(int s0 = 0; s0 < 256; s0 += 64){
        __syncthreads();
        for(int j=0;j<4;j++){
            int lin = t + 256*j;
            int row = lin >> 4;
            int c4  = (lin & 15) * 4;
            size_t gr = (size_t)(b*SS + sc*256 + s0 + row);
            ushort4 kv = *(const ushort4*)(qkv + gr*3072 + DD + h*64 + c4);
            float4 kf; kf.x=b2f(kv.x); kf.y=b2f(kv.y); kf.z=b2f(kv.z); kf.w=b2f(kv.w);
            *(float4*)&kl[row][c4] = kf;
            ushort4 vv = *(const ushort4*)(qkv + gr*3072 + 2*DD + h*64 + c4);
            float4 vf; vf.x=b2f(vv.x); vf.y=b2f(vv.y); vf.z=b2f(vv.z); vf.w=b2f(vv.w);
            *(float4*)&vl[row][c4] = vf;
        }
        __syncthreads();
        for(int s=0;s<64;s++){
            float ve = vl[s][e];
            #pragma unroll
            for(int di=0; di<16; di++) acc[di] += kl[s][dg+di] * ve;
        }
    }
    float* cbase = ctx + (size_t)(b*HH + h)*4096;
    for(int di=0; di<16; di++) atomicAdd(&cbase[(dg+di)*64 + e], acc[di]);
}

// ---------------------------------------------------------------- attn[n,h*64+e] = sum_d q[n,h*64+d]*ctx[b,h,d,e]
// q read from QKV (softmaxed in-place), output to Abuf [M,1024]
__global__ __launch_bounds__(256) void attn_heads(const unsigned short* __restrict__ qkv,
                                                  const float* __restrict__ ctx,
                                                  unsigned short* __restrict__ abuf){
    int rg = blockIdx.x, h = blockIdx.y;
    int b = rg >> 6;
    int t = threadIdx.x;
    __shared__ __align__(16) float cl[64][64];
    __shared__ __align__(16) float ql[64][64];
    const float* cb = ctx + (size_t)(b*HH + h)*4096;
    for(int j=0;j<4;j++){
        int lin = t + 256*j;
        ((float4*)cl)[lin] = ((const float4*)cb)[lin];
    }
    for(int j=0;j<4;j++){
        int lin = t + 256*j;
        int row = lin >> 4;
        int c4  = (lin & 15) * 4;
        ushort4 qv = *(const ushort4*)(qkv + (size_t)(rg*64+row)*3072 + h*64 + c4);
        float4 qf; qf.x=b2f(qv.x); qf.y=b2f(qv.y); qf.z=b2f(qv.z); qf.w=b2f(qv.w);
        *(float4*)&ql[row][c4] = qf;
    }
    __syncthreads();
    int e = t & 63, rbase = (t >> 6) * 16;
    float acc[16] = {};
    for(int d=0; d<64; d++){
        float cv = cl[d][e];
        #pragma unroll
        for(int ri=0; ri<16; ri++) acc[ri] += ql[rbase+ri][d] * cv;
    }
    for(int ri=0; ri<16; ri++)
        abuf[(size_t)(rg*64 + rbase + ri)*DD + h*64 + e] = f2b(acc[ri]);
}

// ---------------------------------------------------------------- launch
extern "C" void kernel_launch(void* const* d_in, const int* in_sizes, int n_in,
                              void* d_out, int out_size, void* d_ws, size_t ws_size,
                              hipStream_t stream)
{
    const float* x     = (const float*)d_in[0];
    const float* ln1_g = (const float*)d_in[1];
    const float* ln1_b = (const float*)d_in[2];
    const float* w_qkv = (const float*)d_in[3];
    const float* w_out = (const float*)d_in[4];
    const float* b_out = (const float*)d_in[5];
    const float* ln2_g = (const float*)d_in[6];
    const float* ln2_b = (const float*)d_in[7];
    const float* w1    = (const float*)d_in[8];
    const float* b1    = (const float*)d_in[9];
    const float* w2    = (const float*)d_in[10];
    const float* b2    = (const float*)d_in[11];
    const float* w3    = (const float*)d_in[12];
    const float* b3    = (const float*)d_in[13];

    // ---- workspace layout (peak 184 MB; aliases are temporally disjoint) ----
    char* ws = (char*)d_ws;
    unsigned short* wqkvT = (unsigned short*)(ws + 0);            // 3072x1024 bf16, 6291456 B
    unsigned short* woutT = (unsigned short*)(ws + 6291456);      // 1024x1024 bf16, 2097152 B
    unsigned short* w1T   = (unsigned short*)(ws + 8388608);      // 2048x1024 bf16, 4194304 B
    unsigned short* w2T   = (unsigned short*)(ws + 12582912);     // 2048x2048 bf16, 8388608 B
    unsigned short* w3T   = (unsigned short*)(ws + 20971520);     // 1024x2048 bf16, 4194304 B
    // phase 1: ln1 out (bf16 [M,1024])
    unsigned short* Hbuf  = (unsigned short*)(ws + 25165824);     // 32 MB, dead after qkv gemm
    unsigned short* QKV   = (unsigned short*)(ws + 58720256);     // [M,3072] bf16, 96 MB, dead after attn_heads
    float*          CTX   = (float*)(ws + 159383552);             // 64*64*64 f32 = 1 MB (attention phase only)
    float*          colsum= (float*)(ws + 160432128);             // 4096 f32 (attention phase only)
    // phase 2 aliases:
    unsigned short* Abuf  = Hbuf;                                 // attn out [M,1024] bf16 (alias Hbuf)
    float*          X2    = (float*)(ws + 58720256);              // x+attn f32 [M,1024], 64 MB (alias QKV head)
    unsigned short* H2    = Hbuf;                                 // ln2 out (alias Abuf after consumed)
    unsigned short* Y1    = (unsigned short*)d_out;               // [M,2048] bf16 = 64 MB = out_size bytes exactly
    unsigned short* Y2    = (unsigned short*)(ws + 125829120);    // [M,2048] bf16, 64 MB (alias QKV tail + CTX)

    dim3 tb(32, 8);
    transpose_cvt<<<dim3(3072/32, 1024/32), tb, 0, stream>>>(w_qkv, wqkvT, 1024, 3072);
    transpose_cvt<<<dim3(1024/32, 1024/32), tb, 0, stream>>>(w_out, woutT, 1024, 1024);
    transpose_cvt<<<dim3(2048/32, 1024/32), tb, 0, stream>>>(w1,    w1T,   1024, 2048);
    transpose_cvt<<<dim3(2048/32, 2048/32), tb, 0, stream>>>(w2,    w2T,   2048, 2048);
    transpose_cvt<<<dim3(1024/32, 2048/32), tb, 0, stream>>>(w3,    w3T,   2048, 1024);

    // zero CTX + colsum (contiguous: 262144 + 4096 floats)
    zero_f32<<<(266240 + 255)/256, 256, 0, stream>>>(CTX, 266240);

    ln_kernel<<<MM, 256, 0, stream>>>(x, ln1_g, ln1_b, Hbuf, 1);

    gemm_bt<0><<<dim3(3072/128, MM/128), 256, 0, stream>>>(Hbuf, wqkvT, QKV, nullptr, nullptr, MM, 3072, 1024);

    q_softmax<<<MM, 256, 0, stream>>>(QKV);
    k_colsum<<<dim3(16, 16, 4), 256, 0, stream>>>(QKV, colsum);
    k_norm<<<MM, 256, 0, stream>>>(QKV, colsum);
    ctx_partial<<<dim3(16, 16, 4), 256, 0, stream>>>(QKV, CTX);
    attn_heads<<<dim3(256, 16), 256, 0, stream>>>(QKV, CTX, Abuf);

    gemm_bt<2><<<dim3(1024/128, MM/128), 256, 0, stream>>>(Abuf, woutT, X2, b_out, x, MM, 1024, 1024);

    ln_kernel<<<MM, 256, 0, stream>>>(X2, ln2_g, ln2_b, H2, 0);

    gemm_bt<1><<<dim3(2048/128, MM/128), 256, 0, stream>>>(H2, w1T, Y1, b1, nullptr, MM, 2048, 1024);
    gemm_bt<1><<<dim3(2048/128, MM/128), 256, 0, stream>>>(Y1, w2T, Y2, b2, nullptr, MM, 2048, 2048);
    gemm_bt<2><<<dim3(1024/128, MM/128), 256, 0, stream>>>(Y2, w3T, d_out, b3, X2, MM, 1024, 2048);
}

// Round 4
// 791.667 us; speedup vs baseline: 1.0911x; 1.0911x over previous
//
#include <hip/hip_runtime.h>
#include <cstdint>
#include <cstddef>

// Problem constants
#define BB 4
#define SS 4096
#define DD 1024
#define HH 16
#define MM (BB*SS)          // 16384 rows

typedef __bf16 bf16x8 __attribute__((ext_vector_type(8)));
typedef float  f32x4  __attribute__((ext_vector_type(4)));

__device__ __forceinline__ float b2f(unsigned short h){
    union { unsigned int u; float f; } c; c.u = ((unsigned int)h) << 16; return c.f;
}
__device__ __forceinline__ unsigned short f2b(float f){
    union { float f; unsigned int u; } c; c.f = f;
    unsigned int u = c.u + 0x7FFFu + ((c.u >> 16) & 1u);   // RNE
    return (unsigned short)(u >> 16);
}

// ---------------------------------------------------------------- transpose+cvt
__global__ void transpose_cvt(const float* __restrict__ src, unsigned short* __restrict__ dst,
                              int K, int N){
    __shared__ float tile[32][33];
    int kb = blockIdx.y*32, nb = blockIdx.x*32;
    int tx = threadIdx.x, ty = threadIdx.y;
    for(int i=0;i<32;i+=8) tile[ty+i][tx] = src[(size_t)(kb+ty+i)*N + nb+tx];
    __syncthreads();
    for(int i=0;i<32;i+=8) dst[(size_t)(nb+ty+i)*K + kb+tx] = f2b(tile[tx][ty+i]);
}

// ---------------------------------------------------------------- layernorm (+ optional sinusoidal PE)
__global__ __launch_bounds__(256) void ln_kernel(const float* __restrict__ x,
                                                 const float* __restrict__ g,
                                                 const float* __restrict__ bta,
                                                 unsigned short* __restrict__ out,
                                                 int add_pe){
    int row = blockIdx.x;
    int t = threadIdx.x;
    float4 v = ((const float4*)(x + (size_t)row*DD))[t];
    float s = v.x+v.y+v.z+v.w;
    float q = v.x*v.x+v.y*v.y+v.z*v.z+v.w*v.w;
    for(int off=32; off>0; off>>=1){ s += __shfl_xor(s, off); q += __shfl_xor(q, off); }
    __shared__ float red[8];
    int wv = t>>6, ln = t&63;
    if(ln==0){ red[wv] = s; red[4+wv] = q; }
    __syncthreads();
    s = red[0]+red[1]+red[2]+red[3];
    q = red[4]+red[5]+red[6]+red[7];
    float mu = s * (1.0f/1024.0f);
    float var = q * (1.0f/1024.0f) - mu*mu;
    float rs = rsqrtf(var + 1e-6f);
    int d0 = t*4;
    float4 gg = ((const float4*)g)[t];
    float4 bb = ((const float4*)bta)[t];
    float o0 = (v.x-mu)*rs*gg.x + bb.x;
    float o1 = (v.y-mu)*rs*gg.y + bb.y;
    float o2 = (v.z-mu)*rs*gg.z + bb.z;
    float o3 = (v.w-mu)*rs*gg.w + bb.w;
    if(add_pe){
        int sidx = row & (SS-1);
        const float cfac = -0.008994473019508968f;   // -ln(10000)/1024
        float a0 = (float)sidx * expf(cfac * (float)(d0));
        float a1 = (float)sidx * expf(cfac * (float)(d0 + 2));
        o0 += sinf(a0); o1 += cosf(a0);
        o2 += sinf(a1); o3 += cosf(a1);
    }
    ushort4 o;
    o.x = f2b(o0); o.y = f2b(o1); o.z = f2b(o2); o.w = f2b(o3);
    *(ushort4*)(out + (size_t)row*DD + d0) = o;
}

// ---------------------------------------------------------------- bf16 MFMA GEMM  C = A[M,K] * Bt[N,K]^T
// XCD-swizzled tiles: XCD x owns m-tiles == x (mod 8), streams n per m-group (A L2-resident).
template<int EPI>
__global__ __launch_bounds__(256, 2) void gemm_bt(
        const unsigned short* __restrict__ A,
        const unsigned short* __restrict__ Bt,
        void* __restrict__ Cout,
        const float* __restrict__ bias,
        const float* __restrict__ resid,
        int M, int N, int K)
{
    __shared__ __align__(16) unsigned short lA[128*64];
    __shared__ __align__(16) unsigned short lB[128*64];
    const int tid  = threadIdx.x;
    const int lane = tid & 63;
    const int wave = tid >> 6;
    const int quad = lane >> 4;
    const int l16  = lane & 15;
    const int wr = wave >> 1, wc = wave & 1;

    // XCD-aware tile swizzle (grid m-tiles divisible by 8 here)
    int gn  = gridDim.x;
    int lin = blockIdx.y * gn + blockIdx.x;
    int xcd = lin & 7;
    int j   = lin >> 3;
    int mt  = xcd + 8*(j/gn);
    int nt  = j - (j/gn)*gn;
    const int m0 = mt * 128;
    const int n0 = nt * 128;

    f32x4 acc[4][4] = {};

    for (int k0 = 0; k0 < K; k0 += 64) {
        __syncthreads();
        #pragma unroll
        for (int i = 0; i < 4; i++) {
            int c   = tid + 256*i;
            int row = c >> 3;
            int kc  = ((c & 7) ^ (row & 7)) << 3;          // XOR swizzle (elements)
            const unsigned short* gA = A  + (size_t)(m0 + row) * K + k0 + kc;
            const unsigned short* gB = Bt + (size_t)(n0 + row) * K + k0 + kc;
            char* lpA = ((char*)lA) + (wave<<10) + (i<<12); // wave-uniform base; HW adds lane*16
            char* lpB = ((char*)lB) + (wave<<10) + (i<<12);
            __builtin_amdgcn_global_load_lds((const __attribute__((address_space(1))) void*)gA,
                                             (__attribute__((address_space(3))) void*)lpA, 16, 0, 0);
            __builtin_amdgcn_global_load_lds((const __attribute__((address_space(1))) void*)gB,
                                             (__attribute__((address_space(3))) void*)lpB, 16, 0, 0);
        }
        __syncthreads();
        #pragma unroll
        for (int kk = 0; kk < 2; kk++) {
            bf16x8 af[4], bfr[4];
            #pragma unroll
            for (int mi = 0; mi < 4; mi++) {
                int row = wr*64 + mi*16 + l16;
                int kb  = (kk*64 + quad*16) ^ ((row & 7) << 4);
                af[mi] = *(const bf16x8*)((const char*)lA + row*128 + kb);
            }
            #pragma unroll
            for (int ni = 0; ni < 4; ni++) {
                int row = wc*64 + ni*16 + l16;
                int kb  = (kk*64 + quad*16) ^ ((row & 7) << 4);
                bfr[ni] = *(const bf16x8*)((const char*)lB + row*128 + kb);
            }
            #pragma unroll
            for (int mi = 0; mi < 4; mi++)
                #pragma unroll
                for (int ni = 0; ni < 4; ni++)
                    acc[mi][ni] = __builtin_amdgcn_mfma_f32_16x16x32_bf16(af[mi], bfr[ni], acc[mi][ni], 0, 0, 0);
        }
    }

    #pragma unroll
    for (int mi = 0; mi < 4; mi++) {
        #pragma unroll
        for (int r = 0; r < 4; r++) {
            int grow = m0 + wr*64 + mi*16 + quad*4 + r;
            #pragma unroll
            for (int ni = 0; ni < 4; ni++) {
                int gcol = n0 + wc*64 + ni*16 + l16;
                float v = acc[mi][ni][r];
                size_t idx = (size_t)grow * N + gcol;
                if (EPI == 0) {
                    ((unsigned short*)Cout)[idx] = f2b(v);
                } else if (EPI == 1) {
                    v += bias[gcol];
                    v = 0.5f * v * (1.0f + erff(v * 0.70710678118654752f));
                    ((unsigned short*)Cout)[idx] = f2b(v);
                } else {
                    v += bias[gcol] + resid[idx];
                    ((float*)Cout)[idx] = v;
                }
            }
        }
    }
}

// ---------------------------------------------------------------- context partials (k-softmax folded)
// E_slot[d,e] = sum_s exp(k[s,d]) * v[s,e] ;  cs_slot[d] = sum_s exp(k[s,d])
// grid (sc=16, h=16, b=4); private slot per block -> no atomics, no zero-init.
__global__ __launch_bounds__(256) void ctx_partial(const unsigned short* __restrict__ qkv,
                                                   float* __restrict__ EP,
                                                   float* __restrict__ CS){
    int sc = blockIdx.x, h = blockIdx.y, b = blockIdx.z;
    int t = threadIdx.x;
    __shared__ __align__(16) float kl[64][64];   // exp(k)
    __shared__ __align__(16) float vl[64][64];
    __shared__ float csred[4][64];
    float acc[16] = {};
    float cspart = 0.0f;
    int e = t & 63, dg = (t >> 6) * 16;
    int dcol = t & 63, schunk = t >> 6;
    for(int s0 = 0; s0 < 256; s0 += 64){
        __syncthreads();
        for(int j=0;j<4;j++){
            int lin = t + 256*j;
            int row = lin >> 4;
            int c4  = (lin & 15) * 4;
            size_t gr = (size_t)(b*SS + sc*256 + s0 + row);
            ushort4 kv = *(const ushort4*)(qkv + gr*3072 + DD + h*64 + c4);
            float4 kf; kf.x=expf(b2f(kv.x)); kf.y=expf(b2f(kv.y)); kf.z=expf(b2f(kv.z)); kf.w=expf(b2f(kv.w));
            *(float4*)&kl[row][c4] = kf;
            ushort4 vv = *(const ushort4*)(qkv + gr*3072 + 2*DD + h*64 + c4);
            float4 vf; vf.x=b2f(vv.x); vf.y=b2f(vv.y); vf.z=b2f(vv.z); vf.w=b2f(vv.w);
            *(float4*)&vl[row][c4] = vf;
        }
        __syncthreads();
        #pragma unroll
        for(int i=0;i<16;i++) cspart += kl[schunk*16+i][dcol];
        for(int s=0;s<64;s++){
            float ve = vl[s][e];
            #pragma unroll
            for(int di=0; di<16; di++) acc[di] += kl[s][dg+di] * ve;
        }
    }
    int slot = (b*HH + h)*16 + sc;
    float* ep = EP + (size_t)slot*4096;
    #pragma unroll
    for(int di=0; di<16; di++) ep[(dg+di)*64 + e] = acc[di];
    csred[schunk][dcol] = cspart;
    __syncthreads();
    if(t < 64) CS[slot*64 + t] = csred[0][t]+csred[1][t]+csred[2][t]+csred[3][t];
}

// ---------------------------------------------------------------- reduce 16 slots, divide by colsum
// CTXF[(b,h), d*64+e] = sum_slots E / sum_slots cs[d]     grid: 64 blocks (b*16+h)
__global__ __launch_bounds__(256) void ctx_reduce(const float* __restrict__ EP,
                                                  const float* __restrict__ CS,
                                                  float* __restrict__ CTXF){
    int bh = blockIdx.x;
    int t = threadIdx.x;
    int d = t >> 2, e0 = (t & 3) * 16;
    float cs = 0.0f;
    #pragma unroll
    for(int sl=0; sl<16; sl++) cs += CS[(bh*16+sl)*64 + d];
    float inv = 1.0f/cs;
    #pragma unroll
    for(int i=0;i<16;i++){
        float s = 0.0f;
        #pragma unroll
        for(int sl=0; sl<16; sl++) s += EP[(size_t)(bh*16+sl)*4096 + d*64 + e0 + i];
        CTXF[(size_t)bh*4096 + d*64 + e0 + i] = s * inv;
    }
}

// ---------------------------------------------------------------- attn = softmax(q)/8 @ ctx  (q-softmax fused)
// grid (rg=256, h=16); q raw from QKV; out Abuf[M,1024]
__global__ __launch_bounds__(256) void attn_heads(const unsigned short* __restrict__ qkv,
                                                  const float* __restrict__ CTXF,
                                                  unsigned short* __restrict__ abuf){
    int rg = blockIdx.x, h = blockIdx.y;
    int b = rg >> 6;
    int t = threadIdx.x;
    __shared__ __align__(16) float cl[64][64];
    __shared__ float ql[64*65];                   // row stride 65: scalar stores 2-way aliased (free)
    const float* cb = CTXF + (size_t)(b*HH + h)*4096;
    for(int j=0;j<4;j++){
        int lin = t + 256*j;
        ((float4*)cl)[lin] = ((const float4*)cb)[lin];
    }
    // load q row-segment, softmax in registers, store scaled to LDS
    {
        int r = t >> 2, seg = (t & 3) * 16;
        const unsigned short* qp = qkv + (size_t)(rg*64 + r)*3072 + h*64 + seg;
        float vals[16];
        float m = -1e30f;
        #pragma unroll
        for(int u=0; u<4; u++){
            ushort4 qv = *(const ushort4*)(qp + u*4);
            vals[u*4+0]=b2f(qv.x); vals[u*4+1]=b2f(qv.y); vals[u*4+2]=b2f(qv.z); vals[u*4+3]=b2f(qv.w);
        }
        #pragma unroll
        for(int i=0;i<16;i++) m = fmaxf(m, vals[i]);
        m = fmaxf(m, __shfl_xor(m, 1));
        m = fmaxf(m, __shfl_xor(m, 2));
        float ssum = 0.0f;
        #pragma unroll
        for(int i=0;i<16;i++){ vals[i] = expf(vals[i]-m); ssum += vals[i]; }
        ssum += __shfl_xor(ssum, 1);
        ssum += __shfl_xor(ssum, 2);
        float scl = 0.125f/ssum;
        #pragma unroll
        for(int i=0;i<16;i++) ql[r*65 + seg + i] = vals[i]*scl;
    }
    __syncthreads();
    int e = t & 63, rbase = (t >> 6) * 16;
    float acc2[16] = {};
    for(int d=0; d<64; d++){
        float cv = cl[d][e];
        #pragma unroll
        for(int ri=0; ri<16; ri++) acc2[ri] += ql[(rbase+ri)*65 + d] * cv;
    }
    #pragma unroll
    for(int ri=0; ri<16; ri++)
        abuf[(size_t)(rg*64 + rbase + ri)*DD + h*64 + e] = f2b(acc2[ri]);
}

// ---------------------------------------------------------------- launch
extern "C" void kernel_launch(void* const* d_in, const int* in_sizes, int n_in,
                              void* d_out, int out_size, void* d_ws, size_t ws_size,
                              hipStream_t stream)
{
    const float* x     = (const float*)d_in[0];
    const float* ln1_g = (const float*)d_in[1];
    const float* ln1_b = (const float*)d_in[2];
    const float* w_qkv = (const float*)d_in[3];
    const float* w_out = (const float*)d_in[4];
    const float* b_out = (const float*)d_in[5];
    const float* ln2_g = (const float*)d_in[6];
    const float* ln2_b = (const float*)d_in[7];
    const float* w1    = (const float*)d_in[8];
    const float* b1    = (const float*)d_in[9];
    const float* w2    = (const float*)d_in[10];
    const float* b2    = (const float*)d_in[11];
    const float* w3    = (const float*)d_in[12];
    const float* b3    = (const float*)d_in[13];

    // ---- workspace layout (peak 184 MB; aliases temporally disjoint) ----
    char* ws = (char*)d_ws;
    unsigned short* wqkvT = (unsigned short*)(ws + 0);            // 6291456 B
    unsigned short* woutT = (unsigned short*)(ws + 6291456);      // 2097152 B
    unsigned short* w1T   = (unsigned short*)(ws + 8388608);      // 4194304 B
    unsigned short* w2T   = (unsigned short*)(ws + 12582912);     // 8388608 B
    unsigned short* w3T   = (unsigned short*)(ws + 20971520);     // 4194304 B
    unsigned short* Hbuf  = (unsigned short*)(ws + 25165824);     // 32 MB (ln1 out; later Abuf/H2)
    unsigned short* QKV   = (unsigned short*)(ws + 58720256);     // 96 MB (dead after attn)
    float*          EP    = (float*)(ws + 159383552);             // 1024 slots x 4096 f32 = 16 MB
    float*          CS    = (float*)(ws + 176160768);             // 1024 x 64 f32 = 256 KB
    float*          CTXF  = (float*)(ws + 176422912);             // 64 x 4096 f32 = 1 MB
    // phase 2 aliases:
    unsigned short* Abuf  = Hbuf;
    float*          X2    = (float*)(ws + 58720256);              // 64 MB (alias QKV head)
    unsigned short* H2    = Hbuf;
    unsigned short* Y1    = (unsigned short*)d_out;               // [M,2048] bf16 = out buffer
    unsigned short* Y2    = (unsigned short*)(ws + 125829120);    // 64 MB (alias QKV tail / EP region)

    dim3 tb(32, 8);
    transpose_cvt<<<dim3(3072/32, 1024/32), tb, 0, stream>>>(w_qkv, wqkvT, 1024, 3072);
    transpose_cvt<<<dim3(1024/32, 1024/32), tb, 0, stream>>>(w_out, woutT, 1024, 1024);
    transpose_cvt<<<dim3(2048/32, 1024/32), tb, 0, stream>>>(w1,    w1T,   1024, 2048);
    transpose_cvt<<<dim3(2048/32, 2048/32), tb, 0, stream>>>(w2,    w2T,   2048, 2048);
    transpose_cvt<<<dim3(1024/32, 2048/32), tb, 0, stream>>>(w3,    w3T,   2048, 1024);

    ln_kernel<<<MM, 256, 0, stream>>>(x, ln1_g, ln1_b, Hbuf, 1);

    gemm_bt<0><<<dim3(3072/128, MM/128), 256, 0, stream>>>(Hbuf, wqkvT, QKV, nullptr, nullptr, MM, 3072, 1024);

    ctx_partial<<<dim3(16, HH, BB), 256, 0, stream>>>(QKV, EP, CS);
    ctx_reduce<<<BB*HH, 256, 0, stream>>>(EP, CS, CTXF);
    attn_heads<<<dim3(256, HH), 256, 0, stream>>>(QKV, CTXF, Abuf);

    gemm_bt<2><<<dim3(1024/128, MM/128), 256, 0, stream>>>(Abuf, woutT, X2, b_out, x, MM, 1024, 1024);

    ln_kernel<<<MM, 256, 0, stream>>>(X2, ln2_g, ln2_b, H2, 0);

    gemm_bt<1><<<dim3(2048/128, MM/128), 256, 0, stream>>>(H2, w1T, Y1, b1, nullptr, MM, 2048, 1024);
    gemm_bt<1><<<dim3(2048/128, MM/128), 256, 0, stream>>>(Y1, w2T, Y2, b2, nullptr, MM, 2048, 2048);
    gemm_bt<2><<<dim3(1024/128, MM/128), 256, 0, stream>>>(Y2, w3T, d_out, b3, X2, MM, 1024, 2048);
}

// Round 5
// 730.640 us; speedup vs baseline: 1.1823x; 1.0835x over previous
//
#include <hip/hip_runtime.h>
#include <cstdint>
#include <cstddef>

// Problem constants
#define BB 4
#define SS 4096
#define DD 1024
#define HH 16
#define MM (BB*SS)          // 16384 rows

typedef __bf16 bf16x8 __attribute__((ext_vector_type(8)));
typedef float  f32x4  __attribute__((ext_vector_type(4)));

__device__ __forceinline__ float b2f(unsigned short h){
    union { unsigned int u; float f; } c; c.u = ((unsigned int)h) << 16; return c.f;
}
__device__ __forceinline__ float b2f_u(unsigned int u16){
    union { unsigned int u; float f; } c; c.u = u16 << 16; return c.f;
}
__device__ __forceinline__ unsigned short f2b(float f){
    union { float f; unsigned int u; } c; c.f = f;
    unsigned int u = c.u + 0x7FFFu + ((c.u >> 16) & 1u);   // RNE
    return (unsigned short)(u >> 16);
}

// ---------------------------------------------------------------- transpose+cvt
__global__ void transpose_cvt(const float* __restrict__ src, unsigned short* __restrict__ dst,
                              int K, int N){
    __shared__ float tile[32][33];
    int kb = blockIdx.y*32, nb = blockIdx.x*32;
    int tx = threadIdx.x, ty = threadIdx.y;
    for(int i=0;i<32;i+=8) tile[ty+i][tx] = src[(size_t)(kb+ty+i)*N + nb+tx];
    __syncthreads();
    for(int i=0;i<32;i+=8) dst[(size_t)(nb+ty+i)*K + kb+tx] = f2b(tile[tx][ty+i]);
}

// ---------------------------------------------------------------- layernorm (+ optional sinusoidal PE)
// INBF=0: fp32 input; INBF=1: bf16 input
template<int INBF>
__global__ __launch_bounds__(256) void ln_kernel(const void* __restrict__ xin,
                                                 const float* __restrict__ g,
                                                 const float* __restrict__ bta,
                                                 unsigned short* __restrict__ out,
                                                 int add_pe){
    int row = blockIdx.x;
    int t = threadIdx.x;
    float4 v;
    if (INBF == 0) {
        v = ((const float4*)((const float*)xin + (size_t)row*DD))[t];
    } else {
        ushort4 u = ((const ushort4*)((const unsigned short*)xin + (size_t)row*DD))[t];
        v.x = b2f(u.x); v.y = b2f(u.y); v.z = b2f(u.z); v.w = b2f(u.w);
    }
    float s = v.x+v.y+v.z+v.w;
    float q = v.x*v.x+v.y*v.y+v.z*v.z+v.w*v.w;
    for(int off=32; off>0; off>>=1){ s += __shfl_xor(s, off); q += __shfl_xor(q, off); }
    __shared__ float red[8];
    int wv = t>>6, ln = t&63;
    if(ln==0){ red[wv] = s; red[4+wv] = q; }
    __syncthreads();
    s = red[0]+red[1]+red[2]+red[3];
    q = red[4]+red[5]+red[6]+red[7];
    float mu = s * (1.0f/1024.0f);
    float var = q * (1.0f/1024.0f) - mu*mu;
    float rs = rsqrtf(var + 1e-6f);
    int d0 = t*4;
    float4 gg = ((const float4*)g)[t];
    float4 bb = ((const float4*)bta)[t];
    float o0 = (v.x-mu)*rs*gg.x + bb.x;
    float o1 = (v.y-mu)*rs*gg.y + bb.y;
    float o2 = (v.z-mu)*rs*gg.z + bb.z;
    float o3 = (v.w-mu)*rs*gg.w + bb.w;
    if(add_pe){
        int sidx = row & (SS-1);
        const float cfac = -0.008994473019508968f;   // -ln(10000)/1024
        float a0 = (float)sidx * expf(cfac * (float)(d0));
        float a1 = (float)sidx * expf(cfac * (float)(d0 + 2));
        o0 += sinf(a0); o1 += cosf(a0);
        o2 += sinf(a1); o3 += cosf(a1);
    }
    ushort4 o;
    o.x = f2b(o0); o.y = f2b(o1); o.z = f2b(o2); o.w = f2b(o3);
    *(ushort4*)(out + (size_t)row*DD + d0) = o;
}

// ---------------------------------------------------------------- bf16 MFMA GEMM  C = A[M,K] * Bt[N,K]^T
// EPI 0: store bf16(acc)
// EPI 1: store bf16(gelu(acc+bias[col]))
// EPI 2: store bf16(acc + bias[col] + resid_f32[row,col])     (out-proj -> X2 bf16)
// EPI 3: store f32 (acc + bias[col] + resid_bf16[row,col])    (final output)
template<int EPI>
__global__ __launch_bounds__(256, 2) void gemm_bt(
        const unsigned short* __restrict__ A,
        const unsigned short* __restrict__ Bt,
        void* __restrict__ Cout,
        const float* __restrict__ bias,
        const void* __restrict__ resid,
        int M, int N, int K)
{
    __shared__ __align__(16) unsigned short lA[128*64];
    __shared__ __align__(16) unsigned short lB[128*64];
    const int tid  = threadIdx.x;
    const int lane = tid & 63;
    const int wave = tid >> 6;
    const int quad = lane >> 4;
    const int l16  = lane & 15;
    const int wr = wave >> 1, wc = wave & 1;

    // XCD-aware tile swizzle (m-tiles divisible by 8 here)
    int gn  = gridDim.x;
    int lin = blockIdx.y * gn + blockIdx.x;
    int xcd = lin & 7;
    int j   = lin >> 3;
    int mt  = xcd + 8*(j/gn);
    int nt  = j - (j/gn)*gn;
    const int m0 = mt * 128;
    const int n0 = nt * 128;

    f32x4 acc[4][4] = {};

    for (int k0 = 0; k0 < K; k0 += 64) {
        __syncthreads();
        #pragma unroll
        for (int i = 0; i < 4; i++) {
            int c   = tid + 256*i;
            int row = c >> 3;
            int kc  = ((c & 7) ^ (row & 7)) << 3;          // XOR swizzle (elements)
            const unsigned short* gA = A  + (size_t)(m0 + row) * K + k0 + kc;
            const unsigned short* gB = Bt + (size_t)(n0 + row) * K + k0 + kc;
            char* lpA = ((char*)lA) + (wave<<10) + (i<<12); // wave-uniform base; HW adds lane*16
            char* lpB = ((char*)lB) + (wave<<10) + (i<<12);
            __builtin_amdgcn_global_load_lds((const __attribute__((address_space(1))) void*)gA,
                                             (__attribute__((address_space(3))) void*)lpA, 16, 0, 0);
            __builtin_amdgcn_global_load_lds((const __attribute__((address_space(1))) void*)gB,
                                             (__attribute__((address_space(3))) void*)lpB, 16, 0, 0);
        }
        __syncthreads();
        #pragma unroll
        for (int kk = 0; kk < 2; kk++) {
            bf16x8 af[4], bfr[4];
            #pragma unroll
            for (int mi = 0; mi < 4; mi++) {
                int row = wr*64 + mi*16 + l16;
                int kb  = (kk*64 + quad*16) ^ ((row & 7) << 4);
                af[mi] = *(const bf16x8*)((const char*)lA + row*128 + kb);
            }
            #pragma unroll
            for (int ni = 0; ni < 4; ni++) {
                int row = wc*64 + ni*16 + l16;
                int kb  = (kk*64 + quad*16) ^ ((row & 7) << 4);
                bfr[ni] = *(const bf16x8*)((const char*)lB + row*128 + kb);
            }
            #pragma unroll
            for (int mi = 0; mi < 4; mi++)
                #pragma unroll
                for (int ni = 0; ni < 4; ni++)
                    acc[mi][ni] = __builtin_amdgcn_mfma_f32_16x16x32_bf16(af[mi], bfr[ni], acc[mi][ni], 0, 0, 0);
        }
    }

    #pragma unroll
    for (int mi = 0; mi < 4; mi++) {
        #pragma unroll
        for (int r = 0; r < 4; r++) {
            int grow = m0 + wr*64 + mi*16 + quad*4 + r;
            #pragma unroll
            for (int ni = 0; ni < 4; ni++) {
                int gcol = n0 + wc*64 + ni*16 + l16;
                float v = acc[mi][ni][r];
                size_t idx = (size_t)grow * N + gcol;
                if (EPI == 0) {
                    ((unsigned short*)Cout)[idx] = f2b(v);
                } else if (EPI == 1) {
                    v += bias[gcol];
                    v = 0.5f * v * (1.0f + erff(v * 0.70710678118654752f));
                    ((unsigned short*)Cout)[idx] = f2b(v);
                } else if (EPI == 2) {
                    v += bias[gcol] + ((const float*)resid)[idx];
                    ((unsigned short*)Cout)[idx] = f2b(v);
                } else {
                    v += bias[gcol] + b2f(((const unsigned short*)resid)[idx]);
                    ((float*)Cout)[idx] = v;
                }
            }
        }
    }
}

// ---------------------------------------------------------------- context partials (k-softmax folded)
// E_slot[d,e] = sum_s exp(k[s,d]) * v[s,e] ;  cs_slot[d] = sum_s exp(k[s,d])
// 4x4 register tile per thread: 2 LDS b128 reads per 16 FMA.
__global__ __launch_bounds__(256) void ctx_partial(const unsigned short* __restrict__ qkv,
                                                   float* __restrict__ EP,
                                                   float* __restrict__ CS){
    int sc = blockIdx.x, h = blockIdx.y, b = blockIdx.z;
    int t = threadIdx.x;
    __shared__ __align__(16) float kl[64][64];   // exp(k)
    __shared__ __align__(16) float vl[64][64];
    __shared__ float csred[4][64];
    float acc[4][4] = {};
    float cspart = 0.0f;
    int e4 = (t & 15) * 4, d4 = (t >> 4) * 4;
    int dcol = t & 63, schunk = t >> 6;
    for(int s0 = 0; s0 < 256; s0 += 64){
        __syncthreads();
        #pragma unroll
        for(int j=0;j<2;j++){
            int lin = t + 256*j;
            int row = lin >> 3;
            int c8  = (lin & 7) * 8;
            size_t gr = (size_t)(b*SS + sc*256 + s0 + row);
            uint4 kv = *(const uint4*)(qkv + gr*3072 + DD + h*64 + c8);
            float4 ka, kb2;
            ka.x = expf(b2f_u(kv.x & 0xFFFFu)); ka.y = expf(b2f_u(kv.x >> 16));
            ka.z = expf(b2f_u(kv.y & 0xFFFFu)); ka.w = expf(b2f_u(kv.y >> 16));
            kb2.x = expf(b2f_u(kv.z & 0xFFFFu)); kb2.y = expf(b2f_u(kv.z >> 16));
            kb2.z = expf(b2f_u(kv.w & 0xFFFFu)); kb2.w = expf(b2f_u(kv.w >> 16));
            *(float4*)&kl[row][c8]   = ka;
            *(float4*)&kl[row][c8+4] = kb2;
            uint4 vv = *(const uint4*)(qkv + gr*3072 + 2*DD + h*64 + c8);
            float4 va, vb;
            va.x = b2f_u(vv.x & 0xFFFFu); va.y = b2f_u(vv.x >> 16);
            va.z = b2f_u(vv.y & 0xFFFFu); va.w = b2f_u(vv.y >> 16);
            vb.x = b2f_u(vv.z & 0xFFFFu); vb.y = b2f_u(vv.z >> 16);
            vb.z = b2f_u(vv.w & 0xFFFFu); vb.w = b2f_u(vv.w >> 16);
            *(float4*)&vl[row][c8]   = va;
            *(float4*)&vl[row][c8+4] = vb;
        }
        __syncthreads();
        #pragma unroll
        for(int i=0;i<16;i++) cspart += kl[schunk*16+i][dcol];
        for(int s=0;s<64;s++){
            float4 k4 = *(const float4*)&kl[s][d4];
            float4 v4 = *(const float4*)&vl[s][e4];
            acc[0][0] += k4.x*v4.x; acc[0][1] += k4.x*v4.y; acc[0][2] += k4.x*v4.z; acc[0][3] += k4.x*v4.w;
            acc[1][0] += k4.y*v4.x; acc[1][1] += k4.y*v4.y; acc[1][2] += k4.y*v4.z; acc[1][3] += k4.y*v4.w;
            acc[2][0] += k4.z*v4.x; acc[2][1] += k4.z*v4.y; acc[2][2] += k4.z*v4.z; acc[2][3] += k4.z*v4.w;
            acc[3][0] += k4.w*v4.x; acc[3][1] += k4.w*v4.y; acc[3][2] += k4.w*v4.z; acc[3][3] += k4.w*v4.w;
        }
    }
    int slot = (b*HH + h)*16 + sc;
    float* ep = EP + (size_t)slot*4096;
    #pragma unroll
    for(int i=0;i<4;i++)
        *(float4*)&ep[(d4+i)*64 + e4] = *(float4*)&acc[i][0];
    csred[schunk][dcol] = cspart;
    __syncthreads();
    if(t < 64) CS[slot*64 + t] = csred[0][t]+csred[1][t]+csred[2][t]+csred[3][t];
}

// ---------------------------------------------------------------- reduce 16 slots, divide by colsum
__global__ __launch_bounds__(256) void ctx_reduce(const float* __restrict__ EP,
                                                  const float* __restrict__ CS,
                                                  float* __restrict__ CTXF){
    int bh = blockIdx.x;
    int t = threadIdx.x;
    int d = t >> 2, e0 = (t & 3) * 16;
    float cs = 0.0f;
    #pragma unroll
    for(int sl=0; sl<16; sl++) cs += CS[(bh*16+sl)*64 + d];
    float inv = 1.0f/cs;
    #pragma unroll
    for(int i=0;i<16;i++){
        float s = 0.0f;
        #pragma unroll
        for(int sl=0; sl<16; sl++) s += EP[(size_t)(bh*16+sl)*4096 + d*64 + e0 + i];
        CTXF[(size_t)bh*4096 + d*64 + e0 + i] = s * inv;
    }
}

// ---------------------------------------------------------------- attn = softmax(q)/8 @ ctx  (q-softmax fused)
// ql stored transposed [d][r] (stride 68); 4x4 register tile: 2 b128 per 16 FMA.
__global__ __launch_bounds__(256) void attn_heads(const unsigned short* __restrict__ qkv,
                                                  const float* __restrict__ CTXF,
                                                  unsigned short* __restrict__ abuf){
    int rg = blockIdx.x, h = blockIdx.y;
    int b = rg >> 6;
    int t = threadIdx.x;
    __shared__ __align__(16) float cl[64][64];
    __shared__ __align__(16) float qlT[64*68];    // [d][r], row stride 68 floats
    const float* cb = CTXF + (size_t)(b*HH + h)*4096;
    for(int j=0;j<4;j++){
        int lin = t + 256*j;
        ((float4*)cl)[lin] = ((const float4*)cb)[lin];
    }
    // load q row-segment, softmax in registers, store transposed+scaled to LDS
    {
        int r = t >> 2, seg = (t & 3) * 16;
        const unsigned short* qp = qkv + (size_t)(rg*64 + r)*3072 + h*64 + seg;
        float vals[16];
        float m = -1e30f;
        #pragma unroll
        for(int u=0; u<4; u++){
            ushort4 qv = *(const ushort4*)(qp + u*4);
            vals[u*4+0]=b2f(qv.x); vals[u*4+1]=b2f(qv.y); vals[u*4+2]=b2f(qv.z); vals[u*4+3]=b2f(qv.w);
        }
        #pragma unroll
        for(int i=0;i<16;i++) m = fmaxf(m, vals[i]);
        m = fmaxf(m, __shfl_xor(m, 1));
        m = fmaxf(m, __shfl_xor(m, 2));
        float ssum = 0.0f;
        #pragma unroll
        for(int i=0;i<16;i++){ vals[i] = expf(vals[i]-m); ssum += vals[i]; }
        ssum += __shfl_xor(ssum, 1);
        ssum += __shfl_xor(ssum, 2);
        float scl = 0.125f/ssum;
        #pragma unroll
        for(int i=0;i<16;i++) qlT[(seg+i)*68 + r] = vals[i]*scl;
    }
    __syncthreads();
    int e4 = (t & 15) * 4, r4 = (t >> 4) * 4;
    float acc[4][4] = {};
    for(int d=0; d<64; d++){
        float4 q4 = *(const float4*)&qlT[d*68 + r4];
        float4 c4 = *(const float4*)&cl[d][e4];
        acc[0][0] += q4.x*c4.x; acc[0][1] += q4.x*c4.y; acc[0][2] += q4.x*c4.z; acc[0][3] += q4.x*c4.w;
        acc[1][0] += q4.y*c4.x; acc[1][1] += q4.y*c4.y; acc[1][2] += q4.y*c4.z; acc[1][3] += q4.y*c4.w;
        acc[2][0] += q4.z*c4.x; acc[2][1] += q4.z*c4.y; acc[2][2] += q4.z*c4.z; acc[2][3] += q4.z*c4.w;
        acc[3][0] += q4.w*c4.x; acc[3][1] += q4.w*c4.y; acc[3][2] += q4.w*c4.z; acc[3][3] += q4.w*c4.w;
    }
    #pragma unroll
    for(int i=0;i<4;i++){
        ushort4 o;
        o.x = f2b(acc[i][0]); o.y = f2b(acc[i][1]); o.z = f2b(acc[i][2]); o.w = f2b(acc[i][3]);
        *(ushort4*)(abuf + (size_t)(rg*64 + r4 + i)*DD + h*64 + e4) = o;
    }
}

// ---------------------------------------------------------------- launch
extern "C" void kernel_launch(void* const* d_in, const int* in_sizes, int n_in,
                              void* d_out, int out_size, void* d_ws, size_t ws_size,
                              hipStream_t stream)
{
    const float* x     = (const float*)d_in[0];
    const float* ln1_g = (const float*)d_in[1];
    const float* ln1_b = (const float*)d_in[2];
    const float* w_qkv = (const float*)d_in[3];
    const float* w_out = (const float*)d_in[4];
    const float* b_out = (const float*)d_in[5];
    const float* ln2_g = (const float*)d_in[6];
    const float* ln2_b = (const float*)d_in[7];
    const float* w1    = (const float*)d_in[8];
    const float* b1    = (const float*)d_in[9];
    const float* w2    = (const float*)d_in[10];
    const float* b2    = (const float*)d_in[11];
    const float* w3    = (const float*)d_in[12];
    const float* b3    = (const float*)d_in[13];

    // ---- workspace layout (aliases temporally disjoint) ----
    char* ws = (char*)d_ws;
    unsigned short* wqkvT = (unsigned short*)(ws + 0);            // 6291456 B
    unsigned short* woutT = (unsigned short*)(ws + 6291456);      // 2097152 B
    unsigned short* w1T   = (unsigned short*)(ws + 8388608);      // 4194304 B
    unsigned short* w2T   = (unsigned short*)(ws + 12582912);     // 8388608 B
    unsigned short* w3T   = (unsigned short*)(ws + 20971520);     // 4194304 B
    unsigned short* Hbuf  = (unsigned short*)(ws + 25165824);     // 32 MB (ln1 out; later Abuf/H2)
    unsigned short* QKV   = (unsigned short*)(ws + 58720256);     // 96 MB (dead after attn_heads)
    float*          EP    = (float*)(ws + 159383552);             // 16 MB (attn phase)
    float*          CS    = (float*)(ws + 176160768);             // 256 KB
    float*          CTXF  = (float*)(ws + 176422912);             // 1 MB
    // phase 2 aliases:
    unsigned short* Abuf  = Hbuf;
    unsigned short* X2    = (unsigned short*)(ws + 58720256);     // x+attn bf16 [M,1024] (alias QKV head)
    unsigned short* H2    = Hbuf;
    unsigned short* Y1    = (unsigned short*)d_out;               // [M,2048] bf16 = out buffer
    unsigned short* Y2    = (unsigned short*)(ws + 125829120);    // 64 MB (alias QKV tail / EP region)

    dim3 tb(32, 8);
    transpose_cvt<<<dim3(3072/32, 1024/32), tb, 0, stream>>>(w_qkv, wqkvT, 1024, 3072);
    transpose_cvt<<<dim3(1024/32, 1024/32), tb, 0, stream>>>(w_out, woutT, 1024, 1024);
    transpose_cvt<<<dim3(2048/32, 1024/32), tb, 0, stream>>>(w1,    w1T,   1024, 2048);
    transpose_cvt<<<dim3(2048/32, 2048/32), tb, 0, stream>>>(w2,    w2T,   2048, 2048);
    transpose_cvt<<<dim3(1024/32, 2048/32), tb, 0, stream>>>(w3,    w3T,   2048, 1024);

    ln_kernel<0><<<MM, 256, 0, stream>>>(x, ln1_g, ln1_b, Hbuf, 1);

    gemm_bt<0><<<dim3(3072/128, MM/128), 256, 0, stream>>>(Hbuf, wqkvT, QKV, nullptr, nullptr, MM, 3072, 1024);

    ctx_partial<<<dim3(16, HH, BB), 256, 0, stream>>>(QKV, EP, CS);
    ctx_reduce<<<BB*HH, 256, 0, stream>>>(EP, CS, CTXF);
    attn_heads<<<dim3(256, HH), 256, 0, stream>>>(QKV, CTXF, Abuf);

    gemm_bt<2><<<dim3(1024/128, MM/128), 256, 0, stream>>>(Abuf, woutT, X2, b_out, x, MM, 1024, 1024);

    ln_kernel<1><<<MM, 256, 0, stream>>>(X2, ln2_g, ln2_b, H2, 0);

    gemm_bt<1><<<dim3(2048/128, MM/128), 256, 0, stream>>>(H2, w1T, Y1, b1, nullptr, MM, 2048, 1024);
    gemm_bt<1><<<dim3(2048/128, MM/128), 256, 0, stream>>>(Y1, w2T, Y2, b2, nullptr, MM, 2048, 2048);
    gemm_bt<3><<<dim3(1024/128, MM/128), 256, 0, stream>>>(Y2, w3T, d_out, b3, X2, MM, 1024, 2048);
}